// Round 3
// baseline (1155.720 us; speedup 1.0000x reference)
//
#include <hip/hip_runtime.h>
#include <math.h>

#define BQ    8192
#define DIMD  256
#define NSUB  16
#define KC    1024
#define ED    16
#define KLDS  960          // codebook rows staged in LDS (tail 64 via L1/L2)

#define OFF_ZQ   1
#define OFF_OH   (1 + BQ * DIMD)            // 2097153
#define OH_ELEMS (BQ * NSUB * KC)           // 134217728
#define OFF_IDX  (OFF_OH + OH_ELEMS)        // 136314881
#define F4N      ((OH_ELEMS - 4) / 4)       // aligned float4 slots in onehot
#define WEPS     1e-4f                      // candidate window (v-units)

// ---------------------------------------------------------------------------
// numpy pairwise sum-of-squares, n=16 (8-accumulator unroll pattern):
// r_j = q_j + q_{j+8};  ((r0+r1)+(r2+r3)) + ((r4+r5)+(r6+r7))
// ---------------------------------------------------------------------------
__device__ __forceinline__ float np_sumsq16(const float a[16]) {
  float q[16];
#pragma unroll
  for (int i = 0; i < 16; ++i) q[i] = __fmul_rn(a[i], a[i]);
  float r0 = __fadd_rn(q[0], q[8]),  r1 = __fadd_rn(q[1], q[9]);
  float r2 = __fadd_rn(q[2], q[10]), r3 = __fadd_rn(q[3], q[11]);
  float r4 = __fadd_rn(q[4], q[12]), r5 = __fadd_rn(q[5], q[13]);
  float r6 = __fadd_rn(q[6], q[14]), r7 = __fadd_rn(q[7], q[15]);
  return __fadd_rn(__fadd_rn(__fadd_rn(r0, r1), __fadd_rn(r2, r3)),
                   __fadd_rn(__fadd_rn(r4, r5), __fadd_rn(r6, r7)));
}

// ---------------------------------------------------------------------------
// Reference-rounded distance: numpy einsum SOP (SSE 4-lane, mul+add no FMA,
// hadd combine), then d = sqrt(max((z_sq - 2*cross) + e_sq, 0)) step-rounded.
// sqrt via fp64 (correctly rounded; fp64->fp32 double rounding is safe for
// sqrt since 2*24+2 <= 53) — matches CPU IEEE vsqrtps bit-for-bit, unlike
// gfx9 v_sqrt_f32 which is ~1 ulp.
// ---------------------------------------------------------------------------
__device__ __forceinline__ float ref_d(float4 c0, float4 c1, float4 c2, float4 c3,
                                       const float zf[16], float zsq, float esq) {
  float p0  = __fmul_rn(zf[0],  c0.x), p1  = __fmul_rn(zf[1],  c0.y);
  float p2  = __fmul_rn(zf[2],  c0.z), p3  = __fmul_rn(zf[3],  c0.w);
  float p4  = __fmul_rn(zf[4],  c1.x), p5  = __fmul_rn(zf[5],  c1.y);
  float p6  = __fmul_rn(zf[6],  c1.z), p7  = __fmul_rn(zf[7],  c1.w);
  float p8  = __fmul_rn(zf[8],  c2.x), p9  = __fmul_rn(zf[9],  c2.y);
  float p10 = __fmul_rn(zf[10], c2.z), p11 = __fmul_rn(zf[11], c2.w);
  float p12 = __fmul_rn(zf[12], c3.x), p13 = __fmul_rn(zf[13], c3.y);
  float p14 = __fmul_rn(zf[14], c3.z), p15 = __fmul_rn(zf[15], c3.w);
  float L0 = __fadd_rn(__fadd_rn(__fadd_rn(p0, p4), p8),  p12);
  float L1 = __fadd_rn(__fadd_rn(__fadd_rn(p1, p5), p9),  p13);
  float L2 = __fadd_rn(__fadd_rn(__fadd_rn(p2, p6), p10), p14);
  float L3 = __fadd_rn(__fadd_rn(__fadd_rn(p3, p7), p11), p15);
  float cross = __fadd_rn(__fadd_rn(L0, L1), __fadd_rn(L2, L3));
  float t = __fsub_rn(zsq, __fmul_rn(2.0f, cross));
  t = __fadd_rn(t, esq);
  t = fmaxf(t, 0.0f);
  return (float)sqrt((double)t);      // correctly-rounded fp32 sqrt
}

// ---------------------------------------------------------------------------
// Kernel 1: per-(b,n) sequential VQ, fast fmaf scan + ref-rounded re-eval in
// a window; interleaves onehot zero-fill; writes idx (float) and fp32 mean.
// ---------------------------------------------------------------------------
__global__ __launch_bounds__(256, 2) void vq_main(
    const float* __restrict__ z, const float* __restrict__ emb,
    float* __restrict__ out) {
  __shared__ float cb[KLDS * ED];   // 61440 B
  __shared__ float esq[KC];         // 4096 B  (total 65536 B)
  const int tid = threadIdx.x;
  const int bx  = blockIdx.x;
  const int n   = bx & 15;
  const int b   = (bx >> 4) * 256 + tid;
  const float* embn = emb + n * (KC * ED);

  // stage codebook rows [0, KLDS)
  {
    const float4* src = (const float4*)embn;
    float4* dst = (float4*)cb;
    for (int i = tid; i < KLDS * ED / 4; i += 256) dst[i] = src[i];
  }
  __syncthreads();
  // e_sq with the numpy pairwise pattern (bit-exact ref values)
  for (int k = tid; k < KC; k += 256) {
    const float* cr = (k < KLDS) ? (cb + k * 16) : (embn + k * 16);
    float a[16];
#pragma unroll
    for (int i = 0; i < 16; ++i) a[i] = cr[i];
    esq[k] = np_sumsq16(a);
  }
  if (bx == 0 && tid == 0) {
    out[0] = 0.f;                         // loss accumulator
    out[OFF_OH + 0] = 0.f;                // unaligned head of onehot region
    out[OFF_OH + 1] = 0.f;
    out[OFF_OH + 2] = 0.f;
    out[OFF_OH + OH_ELEMS - 1] = 0.f;     // unaligned tail
  }
  __syncthreads();

  // fp32 residual — matches ref's elementwise fp32 chain exactly
  float zf[16], qsum[16];
  {
    const float4* zp = (const float4*)(z + b * DIMD + n * ED);
    float4 a0 = zp[0], a1 = zp[1], a2 = zp[2], a3 = zp[3];
    zf[0]  = a0.x; zf[1]  = a0.y; zf[2]  = a0.z; zf[3]  = a0.w;
    zf[4]  = a1.x; zf[5]  = a1.y; zf[6]  = a1.z; zf[7]  = a1.w;
    zf[8]  = a2.x; zf[9]  = a2.y; zf[10] = a2.z; zf[11] = a2.w;
    zf[12] = a3.x; zf[13] = a3.y; zf[14] = a3.z; zf[15] = a3.w;
  }
#pragma unroll
  for (int i = 0; i < 16; ++i) qsum[i] = 0.f;

  // interleaved zero-fill state (slot-major => coalesced across threads)
  const int gtid = bx * 256 + tid;
  float4* f4 = (float4*)(out + OFF_OH + 3);   // 16B-aligned
  int s = 0;
  int bi = 0;

  for (int dep = 0; dep < 3; ++dep) {
    const float zsq = np_sumsq16(zf);         // ref-exact z_sq for this depth
    float zf2[16];
#pragma unroll
    for (int i = 0; i < 16; ++i) zf2[i] = zf[i] + zf[i];
    float m1 = 3.0e38f, dmin = 3.0e38f;
    bi = 0;
    int cnt = 0;
    for (int k = 0; k < KLDS; ++k) {
      if (cnt == 0) {                     // one fill store every 11 iters
        cnt = 11;
        if (s < 256) {
          int slot = s * 131072 + gtid;
          ++s;
          if (slot < F4N) f4[slot] = make_float4(0.f, 0.f, 0.f, 0.f);
        }
      }
      --cnt;
      const float4* cp = (const float4*)(cb + k * 16);
      float4 c0 = cp[0], c1 = cp[1], c2 = cp[2], c3 = cp[3];
      float a0 = esq[k], a1 = 0.f;        // fast v ~= d^2 - z_sq
      a0 = fmaf(-zf2[0], c0.x, a0);  a1 = fmaf(-zf2[8],  c2.x, a1);
      a0 = fmaf(-zf2[1], c0.y, a0);  a1 = fmaf(-zf2[9],  c2.y, a1);
      a0 = fmaf(-zf2[2], c0.z, a0);  a1 = fmaf(-zf2[10], c2.z, a1);
      a0 = fmaf(-zf2[3], c0.w, a0);  a1 = fmaf(-zf2[11], c2.w, a1);
      a0 = fmaf(-zf2[4], c1.x, a0);  a1 = fmaf(-zf2[12], c3.x, a1);
      a0 = fmaf(-zf2[5], c1.y, a0);  a1 = fmaf(-zf2[13], c3.y, a1);
      a0 = fmaf(-zf2[6], c1.z, a0);  a1 = fmaf(-zf2[14], c3.z, a1);
      a0 = fmaf(-zf2[7], c1.w, a0);  a1 = fmaf(-zf2[15], c3.w, a1);
      float v = a0 + a1;
      if (v < m1 + WEPS) {                // candidate: ref-rounded distance
        float d = ref_d(c0, c1, c2, c3, zf, zsq, esq[k]);
        if (d < dmin) { dmin = d; bi = k; }   // strict < => first-min
      }
      m1 = fminf(m1, v);
    }
    for (int k = KLDS; k < KC; ++k) {     // tail rows via global (L1/L2-hot)
      const float4* cp = (const float4*)(embn + k * 16);
      float4 c0 = cp[0], c1 = cp[1], c2 = cp[2], c3 = cp[3];
      float a0 = esq[k], a1 = 0.f;
      a0 = fmaf(-zf2[0], c0.x, a0);  a1 = fmaf(-zf2[8],  c2.x, a1);
      a0 = fmaf(-zf2[1], c0.y, a0);  a1 = fmaf(-zf2[9],  c2.y, a1);
      a0 = fmaf(-zf2[2], c0.z, a0);  a1 = fmaf(-zf2[10], c2.z, a1);
      a0 = fmaf(-zf2[3], c0.w, a0);  a1 = fmaf(-zf2[11], c2.w, a1);
      a0 = fmaf(-zf2[4], c1.x, a0);  a1 = fmaf(-zf2[12], c3.x, a1);
      a0 = fmaf(-zf2[5], c1.y, a0);  a1 = fmaf(-zf2[13], c3.y, a1);
      a0 = fmaf(-zf2[6], c1.z, a0);  a1 = fmaf(-zf2[14], c3.z, a1);
      a0 = fmaf(-zf2[7], c1.w, a0);  a1 = fmaf(-zf2[15], c3.w, a1);
      float v = a0 + a1;
      if (v < m1 + WEPS) {
        float d = ref_d(c0, c1, c2, c3, zf, zsq, esq[k]);
        if (d < dmin) { dmin = d; bi = k; }
      }
      m1 = fminf(m1, v);
    }
    // subtract selected code (elementwise fp32 — matches ref), accumulate q
    {
      const float4* sp = (const float4*)(embn + bi * 16);
      float4 s0 = sp[0], s1 = sp[1], s2 = sp[2], s3 = sp[3];
      float cv[16] = { s0.x, s0.y, s0.z, s0.w, s1.x, s1.y, s1.z, s1.w,
                       s2.x, s2.y, s2.z, s2.w, s3.x, s3.y, s3.z, s3.w };
#pragma unroll
      for (int i = 0; i < 16; ++i) {
        qsum[i] = __fadd_rn(qsum[i], cv[i]);   // ((q1+q2)+q3) chain
        zf[i]   = __fsub_rn(zf[i], cv[i]);
      }
    }
  }
  // flush any remaining fill quota (normally none: 3*88 issues >= 256)
  for (; s < 256; ++s) {
    int slot = s * 131072 + gtid;
    if (slot < F4N) f4[slot] = make_float4(0.f, 0.f, 0.f, 0.f);
  }
  out[OFF_IDX + b * NSUB + n] = (float)bi;
  {
    float* mp = out + OFF_ZQ + b * DIMD + n * ED;
#pragma unroll
    for (int i = 0; i < 16; ++i) mp[i] = __fdiv_rn(qsum[i], 3.0f);
  }
}

// ---------------------------------------------------------------------------
// Kernel 2: scatter the ones into the (already zeroed) onehot region.
// ---------------------------------------------------------------------------
__global__ void vq_ones(float* __restrict__ out) {
  int g = blockIdx.x * 256 + threadIdx.x;          // 0 .. 131071 == b*16+n
  int k = (int)out[OFF_IDX + g];
  out[OFF_OH + g * KC + k] = 1.0f;
}

// ---------------------------------------------------------------------------
// Kernel 3: z_q = mean @ W + b (in-place on the mean region), straight-through
// output, and loss = 1.25 * mean((z_q - z)^2).  (Huge threshold slack.)
// ---------------------------------------------------------------------------
#define TB 16
__global__ __launch_bounds__(256, 2) void vq_head(
    const float* __restrict__ z, const float* __restrict__ W,
    const float* __restrict__ bias, float* __restrict__ out) {
  __shared__ float ml[TB][DIMD];   // 16KB
  __shared__ double reds[4];
  const int t  = threadIdx.x;
  const int r0 = blockIdx.x * TB;
  for (int j = t; j < TB * DIMD; j += 256) {
    int r = j >> 8, d = j & 255;
    ml[r][d] = out[OFF_ZQ + (r0 + r) * DIMD + d];
  }
  __syncthreads();
  float acc[TB];
#pragma unroll
  for (int r = 0; r < TB; ++r) acc[r] = 0.f;
  for (int d = 0; d < DIMD; ++d) {
    float w = W[d * DIMD + t];                     // coalesced, L2-resident
#pragma unroll
    for (int r = 0; r < TB; ++r) acc[r] = fmaf(ml[r][d], w, acc[r]);
  }
  const float bv = bias[t];
  double lp = 0.0;
#pragma unroll
  for (int r = 0; r < TB; ++r) {
    float zq   = acc[r] + bv;
    float zv   = z[(r0 + r) * DIMD + t];
    float diff = zq - zv;                          // z_q - z
    out[OFF_ZQ + (r0 + r) * DIMD + t] = zv + diff; // straight-through output
    lp += (double)diff * (double)diff;
  }
#pragma unroll
  for (int o = 32; o > 0; o >>= 1) lp += __shfl_down(lp, o);
  if ((t & 63) == 0) reds[t >> 6] = lp;
  __syncthreads();
  if (t == 0) {
    double tot = reds[0] + reds[1] + reds[2] + reds[3];
    atomicAdd(out, (float)(tot * (1.25 / (double)(BQ * DIMD))));
  }
}

extern "C" void kernel_launch(void* const* d_in, const int* in_sizes, int n_in,
                              void* d_out, int out_size, void* d_ws, size_t ws_size,
                              hipStream_t stream) {
  const float* z    = (const float*)d_in[0];
  const float* emb  = (const float*)d_in[1];
  const float* W    = (const float*)d_in[2];
  const float* bias = (const float*)d_in[3];
  float* out = (float*)d_out;
  vq_main<<<dim3((BQ / 256) * NSUB), dim3(256), 0, stream>>>(z, emb, out);
  vq_ones<<<dim3((BQ * NSUB) / 256), dim3(256), 0, stream>>>(out);
  vq_head<<<dim3(BQ / TB), dim3(256), 0, stream>>>(z, W, bias, out);
}

// Round 4
// 1066.646 us; speedup vs baseline: 1.0835x; 1.0835x over previous
//
#include <hip/hip_runtime.h>
#include <math.h>

#define BQ    8192
#define DIMD  256
#define NSUB  16
#define KC    1024
#define ED    16
#define KLDS  832          // codebook rows staged in LDS (tail 192 via L1/L2)
#define PARTS 4
#define RSC   4            // scans (b's) per thread

#define OFF_ZQ   1
#define OFF_OH   (1 + BQ * DIMD)            // 2097153
#define OH_ELEMS (BQ * NSUB * KC)           // 134217728
#define OFF_IDX  (OFF_OH + OH_ELEMS)        // 136314881
#define F4N      ((OH_ELEMS - 4) / 4)       // aligned float4 slots in onehot
#define WEPS     1e-4f                      // candidate window (v-units)

// ---------------------------------------------------------------------------
// numpy pairwise sum-of-squares, n=16 (8-accumulator unroll pattern).
// ---------------------------------------------------------------------------
__device__ __forceinline__ float np_sumsq16(const float a[16]) {
  float q[16];
#pragma unroll
  for (int i = 0; i < 16; ++i) q[i] = __fmul_rn(a[i], a[i]);
  float r0 = __fadd_rn(q[0], q[8]),  r1 = __fadd_rn(q[1], q[9]);
  float r2 = __fadd_rn(q[2], q[10]), r3 = __fadd_rn(q[3], q[11]);
  float r4 = __fadd_rn(q[4], q[12]), r5 = __fadd_rn(q[5], q[13]);
  float r6 = __fadd_rn(q[6], q[14]), r7 = __fadd_rn(q[7], q[15]);
  return __fadd_rn(__fadd_rn(__fadd_rn(r0, r1), __fadd_rn(r2, r3)),
                   __fadd_rn(__fadd_rn(r4, r5), __fadd_rn(r6, r7)));
}

// ---------------------------------------------------------------------------
// Reference-rounded distance (verified in R3): SSE-lane einsum SOP + hadd,
// step-rounded d^2 assembly, fp64 sqrt (correctly rounded -> CPU-bit-exact).
// ---------------------------------------------------------------------------
__device__ __forceinline__ float ref_d(float4 c0, float4 c1, float4 c2, float4 c3,
                                       const float zf[16], float zsq, float esq) {
  float p0  = __fmul_rn(zf[0],  c0.x), p1  = __fmul_rn(zf[1],  c0.y);
  float p2  = __fmul_rn(zf[2],  c0.z), p3  = __fmul_rn(zf[3],  c0.w);
  float p4  = __fmul_rn(zf[4],  c1.x), p5  = __fmul_rn(zf[5],  c1.y);
  float p6  = __fmul_rn(zf[6],  c1.z), p7  = __fmul_rn(zf[7],  c1.w);
  float p8  = __fmul_rn(zf[8],  c2.x), p9  = __fmul_rn(zf[9],  c2.y);
  float p10 = __fmul_rn(zf[10], c2.z), p11 = __fmul_rn(zf[11], c2.w);
  float p12 = __fmul_rn(zf[12], c3.x), p13 = __fmul_rn(zf[13], c3.y);
  float p14 = __fmul_rn(zf[14], c3.z), p15 = __fmul_rn(zf[15], c3.w);
  float L0 = __fadd_rn(__fadd_rn(__fadd_rn(p0, p4), p8),  p12);
  float L1 = __fadd_rn(__fadd_rn(__fadd_rn(p1, p5), p9),  p13);
  float L2 = __fadd_rn(__fadd_rn(__fadd_rn(p2, p6), p10), p14);
  float L3 = __fadd_rn(__fadd_rn(__fadd_rn(p3, p7), p11), p15);
  float cross = __fadd_rn(__fadd_rn(L0, L1), __fadd_rn(L2, L3));
  float t = __fsub_rn(zsq, __fmul_rn(2.0f, cross));
  t = __fadd_rn(t, esq);
  t = fmaxf(t, 0.0f);
  return (float)sqrt((double)t);      // correctly-rounded fp32 sqrt
}

// ---------------------------------------------------------------------------
// Kernel 1: block = 256 scans (b's) x 1 n; thread = 4 scans x 1/4 of k-range.
// One row load serves 4 evaluations (amortizes LDS issue cost). Per-depth
// cross-part argmin merge via packed (d_bits,k) u64 in LDS — exact (d,k)
// lexicographic min == reference first-index argmin.
// ---------------------------------------------------------------------------
__global__ __launch_bounds__(256, 2) void vq_main(
    const float* __restrict__ z, const float* __restrict__ emb,
    float* __restrict__ out) {
  __shared__ float cb[KLDS * ED];                 // 53248 B
  __shared__ float esq[KC];                       // 4096 B
  __shared__ unsigned long long mrg[256 * PARTS]; // 8192 B  (total 65536)
  const int tid   = threadIdx.x;
  const int bx    = blockIdx.x;
  const int n     = bx & 15;
  const int bbase = (bx >> 4) * 256;
  const int part  = tid >> 6;          // 0..3  (== wave id: k-range uniform/wave)
  const int q     = tid & 63;
  const float* embn = emb + n * (KC * ED);

  // stage codebook rows [0, KLDS)
  {
    const float4* src = (const float4*)embn;
    float4* dst = (float4*)cb;
    for (int i = tid; i < KLDS * ED / 4; i += 256) dst[i] = src[i];
  }
  __syncthreads();
  for (int k = tid; k < KC; k += 256) {
    const float* cr = (k < KLDS) ? (cb + k * 16) : (embn + k * 16);
    float a[16];
#pragma unroll
    for (int i = 0; i < 16; ++i) a[i] = cr[i];
    esq[k] = np_sumsq16(a);
  }
  if (bx == 0 && tid == 0) {
    out[0] = 0.f;                         // loss accumulator
    out[OFF_OH + 0] = 0.f;                // unaligned head of onehot region
    out[OFF_OH + 1] = 0.f;
    out[OFF_OH + 2] = 0.f;
    out[OFF_OH + OH_ELEMS - 1] = 0.f;     // unaligned tail
  }
  __syncthreads();

  // 4 fp32 residuals (scans sc = 4q+r, b = bbase+sc)
  float zf[RSC][16];
#pragma unroll
  for (int r = 0; r < RSC; ++r) {
    const float4* zp = (const float4*)(z + (bbase + q * 4 + r) * DIMD + n * ED);
    float4 a0 = zp[0], a1 = zp[1], a2 = zp[2], a3 = zp[3];
    zf[r][0]  = a0.x; zf[r][1]  = a0.y; zf[r][2]  = a0.z; zf[r][3]  = a0.w;
    zf[r][4]  = a1.x; zf[r][5]  = a1.y; zf[r][6]  = a1.z; zf[r][7]  = a1.w;
    zf[r][8]  = a2.x; zf[r][9]  = a2.y; zf[r][10] = a2.z; zf[r][11] = a2.w;
    zf[r][12] = a3.x; zf[r][13] = a3.y; zf[r][14] = a3.z; zf[r][15] = a3.w;
  }

  // interleaved onehot zero-fill (slot-major: coalesced across global tid)
  const int gtid = bx * 256 + tid;
  float4* f4 = (float4*)(out + OFF_OH + 3);
  int s = 0, fcnt = 0;

  const int kbeg = part * 256, kend = kbeg + 256;
  int bsel[3][RSC];
  float zsq[RSC], m1[RSC], dmin[RSC];
  int ki[RSC];

  for (int dep = 0; dep < 3; ++dep) {
#pragma unroll
    for (int r = 0; r < RSC; ++r) {
      zsq[r] = np_sumsq16(zf[r]);
      m1[r] = 3.0e38f; dmin[r] = 3.0e38f; ki[r] = kend - 1;
    }
    auto evalk = [&](int k, float4 c0, float4 c1, float4 c2, float4 c3) {
      const float esqk = esq[k];
      const float eh = 0.5f * esqk;       // exact scaling
#pragma unroll
      for (int r = 0; r < RSC; ++r) {
        float a = eh;                     // v' = 0.5*esq - dot = (d^2-zsq)/2
        a = fmaf(-zf[r][0],  c0.x, a);  a = fmaf(-zf[r][1],  c0.y, a);
        a = fmaf(-zf[r][2],  c0.z, a);  a = fmaf(-zf[r][3],  c0.w, a);
        a = fmaf(-zf[r][4],  c1.x, a);  a = fmaf(-zf[r][5],  c1.y, a);
        a = fmaf(-zf[r][6],  c1.z, a);  a = fmaf(-zf[r][7],  c1.w, a);
        a = fmaf(-zf[r][8],  c2.x, a);  a = fmaf(-zf[r][9],  c2.y, a);
        a = fmaf(-zf[r][10], c2.z, a);  a = fmaf(-zf[r][11], c2.w, a);
        a = fmaf(-zf[r][12], c3.x, a);  a = fmaf(-zf[r][13], c3.y, a);
        a = fmaf(-zf[r][14], c3.z, a);  a = fmaf(-zf[r][15], c3.w, a);
        if (a < m1[r] + WEPS) {           // window: ref-rounded re-eval
          float d = ref_d(c0, c1, c2, c3, zf[r], zsq[r], esqk);
          if (d < dmin[r]) { dmin[r] = d; ki[r] = k; }   // strict < => first-min
        }
        m1[r] = fminf(m1[r], a);
      }
    };
    const int kmid = (kend < KLDS) ? kend : KLDS;
    for (int k = kbeg; k < kmid; ++k) {         // LDS rows
      if (fcnt == 0) {
        fcnt = 3;
        if (s < 256) {
          int slot = s * 131072 + gtid; ++s;
          if (slot < F4N) f4[slot] = make_float4(0.f, 0.f, 0.f, 0.f);
        }
      }
      --fcnt;
      const float4* cp = (const float4*)(cb + k * 16);
      evalk(k, cp[0], cp[1], cp[2], cp[3]);
    }
    for (int k = (kbeg > KLDS ? kbeg : KLDS); k < kend; ++k) {  // global tail
      if (fcnt == 0) {
        fcnt = 3;
        if (s < 256) {
          int slot = s * 131072 + gtid; ++s;
          if (slot < F4N) f4[slot] = make_float4(0.f, 0.f, 0.f, 0.f);
        }
      }
      --fcnt;
      const float4* cp = (const float4*)(embn + k * 16);
      evalk(k, cp[0], cp[1], cp[2], cp[3]);
    }
    // cross-part merge: packed (d_bits<<32)|k — lexicographic (d,k) min
#pragma unroll
    for (int r = 0; r < RSC; ++r)
      mrg[(q * 4 + r) * PARTS + part] =
          ((unsigned long long)__float_as_uint(dmin[r]) << 32) | (unsigned)ki[r];
    __syncthreads();
#pragma unroll
    for (int r = 0; r < RSC; ++r) {
      const unsigned long long* mp = &mrg[(q * 4 + r) * PARTS];
      unsigned long long mb = mp[0];
      if (mp[1] < mb) mb = mp[1];
      if (mp[2] < mb) mb = mp[2];
      if (mp[3] < mb) mb = mp[3];
      int bi = (int)(mb & 0xffffffffull);
      bsel[dep][r] = bi;
      // identical fp32 residual update in all 4 part-threads
      const float4* sp = (bi < KLDS) ? (const float4*)(cb + bi * 16)
                                     : (const float4*)(embn + bi * 16);
      float4 s0 = sp[0], s1 = sp[1], s2 = sp[2], s3 = sp[3];
      float cv[16] = { s0.x, s0.y, s0.z, s0.w, s1.x, s1.y, s1.z, s1.w,
                       s2.x, s2.y, s2.z, s2.w, s3.x, s3.y, s3.z, s3.w };
#pragma unroll
      for (int i = 0; i < 16; ++i) zf[r][i] = __fsub_rn(zf[r][i], cv[i]);
    }
    __syncthreads();   // protect mrg reuse next depth
  }
  // flush remaining fill quota (768/3 = 256 exactly; safety only)
  for (; s < 256; ++s) {
    int slot = s * 131072 + gtid;
    if (slot < F4N) f4[slot] = make_float4(0.f, 0.f, 0.f, 0.f);
  }
  // part 0 writes idx + mean(q) for its 4 scans
  if (part == 0) {
#pragma unroll
    for (int r = 0; r < RSC; ++r) {
      const int b = bbase + q * 4 + r;
      out[OFF_IDX + b * NSUB + n] = (float)bsel[2][r];
      float qs[16];
#pragma unroll
      for (int i = 0; i < 16; ++i) qs[i] = 0.f;
#pragma unroll
      for (int dep = 0; dep < 3; ++dep) {
        int bi = bsel[dep][r];
        const float* cr = (bi < KLDS) ? (cb + bi * 16) : (embn + bi * 16);
#pragma unroll
        for (int i = 0; i < 16; ++i) qs[i] = __fadd_rn(qs[i], cr[i]);
      }
      float* mp2 = out + OFF_ZQ + b * DIMD + n * ED;
#pragma unroll
      for (int i = 0; i < 16; ++i) mp2[i] = __fdiv_rn(qs[i], 3.0f);
    }
  }
}

// ---------------------------------------------------------------------------
// Kernel 2: scatter the ones into the (already zeroed) onehot region.
// ---------------------------------------------------------------------------
__global__ void vq_ones(float* __restrict__ out) {
  int g = blockIdx.x * 256 + threadIdx.x;          // 0 .. 131071 == b*16+n
  int k = (int)out[OFF_IDX + g];
  out[OFF_OH + g * KC + k] = 1.0f;
}

// ---------------------------------------------------------------------------
// Kernel 3: z_q = mean @ W + b, straight-through output, loss.
// ---------------------------------------------------------------------------
#define TB 16
__global__ __launch_bounds__(256, 2) void vq_head(
    const float* __restrict__ z, const float* __restrict__ W,
    const float* __restrict__ bias, float* __restrict__ out) {
  __shared__ float ml[TB][DIMD];   // 16KB
  __shared__ double reds[4];
  const int t  = threadIdx.x;
  const int r0 = blockIdx.x * TB;
  for (int j = t; j < TB * DIMD; j += 256) {
    int r = j >> 8, d = j & 255;
    ml[r][d] = out[OFF_ZQ + (r0 + r) * DIMD + d];
  }
  __syncthreads();
  float acc[TB];
#pragma unroll
  for (int r = 0; r < TB; ++r) acc[r] = 0.f;
  for (int d = 0; d < DIMD; ++d) {
    float w = W[d * DIMD + t];
#pragma unroll
    for (int r = 0; r < TB; ++r) acc[r] = fmaf(ml[r][d], w, acc[r]);
  }
  const float bv = bias[t];
  double lp = 0.0;
#pragma unroll
  for (int r = 0; r < TB; ++r) {
    float zq   = acc[r] + bv;
    float zv   = z[(r0 + r) * DIMD + t];
    float diff = zq - zv;
    out[OFF_ZQ + (r0 + r) * DIMD + t] = zv + diff;
    lp += (double)diff * (double)diff;
  }
#pragma unroll
  for (int o = 32; o > 0; o >>= 1) lp += __shfl_down(lp, o);
  if ((t & 63) == 0) reds[t >> 6] = lp;
  __syncthreads();
  if (t == 0) {
    double tot = reds[0] + reds[1] + reds[2] + reds[3];
    atomicAdd(out, (float)(tot * (1.25 / (double)(BQ * DIMD))));
  }
}

extern "C" void kernel_launch(void* const* d_in, const int* in_sizes, int n_in,
                              void* d_out, int out_size, void* d_ws, size_t ws_size,
                              hipStream_t stream) {
  const float* z    = (const float*)d_in[0];
  const float* emb  = (const float*)d_in[1];
  const float* W    = (const float*)d_in[2];
  const float* bias = (const float*)d_in[3];
  float* out = (float*)d_out;
  vq_main<<<dim3((BQ / 256) * NSUB), dim3(256), 0, stream>>>(z, emb, out);
  vq_ones<<<dim3((BQ * NSUB) / 256), dim3(256), 0, stream>>>(out);
  vq_head<<<dim3(BQ / TB), dim3(256), 0, stream>>>(z, W, bias, out);
}